// Round 3
// baseline (755.924 us; speedup 1.0000x reference)
//
#include <hip/hip_runtime.h>

// Problem constants
#define Bb 2
#define Ll 2048
#define Ee 2048
#define Hh 16
#define Dd 128
#define BL (Bb * Ll)   // 4096
#define NT (Ll / 64)   // 32 k-tiles in attention
#define LOSCALE 1024.0f
#define INV_LOSCALE (1.0f / 1024.0f)
#define LOG2E 1.442695041f

typedef float f32x4 __attribute__((ext_vector_type(4)));
typedef _Float16 f16x8 __attribute__((ext_vector_type(8)));

// Async global->LDS, 16B per lane. Dest = wave-uniform base + lane*16.
// Source is PER-LANE, so XOR swizzles are applied on the source address.
__device__ __forceinline__ void gld_lds16(const void* g, void* l) {
  __builtin_amdgcn_global_load_lds((const __attribute__((address_space(1))) void*)g,
                                   (__attribute__((address_space(3))) void*)l, 16, 0, 0);
}

// Hardware 2^x (v_exp_f32 semantics ARE exp2). Single transcendental op,
// no libm range-check code.
__device__ __forceinline__ float exp2_hw(float x) {
  float r;
  asm("v_exp_f32 %0, %1" : "=v"(r) : "v"(x));
  return r;
}

// ---------------------------------------------------------------------------
// f32 -> f16 plain convert (4 elems / thread)
// ---------------------------------------------------------------------------
__global__ __launch_bounds__(256) void cvt_f32_f16(const float* __restrict__ in,
                                                   _Float16* __restrict__ out, int n4) {
  int i = blockIdx.x * 256 + threadIdx.x;
  if (i < n4) {
    float4 f = ((const float4*)in)[i];
    _Float16 o[4] = {(_Float16)f.x, (_Float16)f.y, (_Float16)f.z, (_Float16)f.w};
    ((uint2*)out)[i] = *(uint2*)o;
  }
}

// ---------------------------------------------------------------------------
// f32 -> split fp16: hi = rn(x), lo = rn((x - hi) * 1024)  (eps^2 precision)
// ---------------------------------------------------------------------------
__global__ __launch_bounds__(256) void cvt_split(const float* __restrict__ in,
                                                 _Float16* __restrict__ hi,
                                                 _Float16* __restrict__ lo, int n4) {
  int i = blockIdx.x * 256 + threadIdx.x;
  if (i < n4) {
    float4 f = ((const float4*)in)[i];
    float fa[4] = {f.x, f.y, f.z, f.w};
    _Float16 h[4], l[4];
    for (int j = 0; j < 4; ++j) {
      h[j] = (_Float16)fa[j];
      l[j] = (_Float16)((fa[j] - (float)h[j]) * LOSCALE);
    }
    ((uint2*)hi)[i] = *(uint2*)h;
    ((uint2*)lo)[i] = *(uint2*)l;
  }
}

// ---------------------------------------------------------------------------
// bias f32 [b][q][k] -> fp16*LOG2E in MFMA-fragment order:
//   [b][qt256][kt][idx16][lane][16], idx16 = wave*2 + m  (wave owns 32 q-rows)
// ---------------------------------------------------------------------------
__global__ __launch_bounds__(256) void bias_perm(const float* __restrict__ bias,
                                                 _Float16* __restrict__ out) {
  __shared__ float T[128][68];
  const int kt = blockIdx.x, qt = blockIdx.y, b = blockIdx.z;  // qt: 128-row units
  const float* src = bias + ((size_t)b * Ll + qt * 128) * Ll + kt * 64;
  const int t = threadIdx.x;
  for (int c = 0; c < 8; ++c) {
    int idx = c * 256 + t;              // 0..2047 float4 chunks
    int r = idx >> 4, col4 = (idx & 15) * 4;
    float4 v = *(const float4*)&src[(size_t)r * Ll + col4];
    T[r][col4 + 0] = v.x; T[r][col4 + 1] = v.y;
    T[r][col4 + 2] = v.z; T[r][col4 + 3] = v.w;
  }
  __syncthreads();
  _Float16* dst = out + ((((size_t)(b * 8 + (qt >> 1)) * NT + kt) * 16 + (qt & 1) * 8) * 64) * 16;
  for (int s = 0; s < 2; ++s) {
    int slot = t + s * 256;             // 0..511 = w16*64 + lane
    int w = slot >> 6, lane = slot & 63;
    int quad = lane >> 4, l16 = lane & 15;
    _Float16 vals[16];
    for (int nt = 0; nt < 4; ++nt)
      for (int r = 0; r < 4; ++r)
        vals[nt * 4 + r] = (_Float16)(T[w * 16 + quad * 4 + r][nt * 16 + l16] * LOG2E);
    *(uint4*)&dst[((size_t)w * 64 + lane) * 16] = *(uint4*)&vals[0];
    *(uint4*)&dst[((size_t)w * 64 + lane) * 16 + 8] = *(uint4*)&vals[8];
  }
}

// ---------------------------------------------------------------------------
// Plain GEMM:  C[M,N] = A[M,K] @ Bw[N,K]^T.
// ---------------------------------------------------------------------------
template <typename OutT>
__global__ __launch_bounds__(256, 2) void gemm_bt(const _Float16* __restrict__ A,
                                                  const _Float16* __restrict__ Bw,
                                                  OutT* __restrict__ C, int M, int N, int K) {
  __shared__ _Float16 As[128 * 64];
  __shared__ _Float16 Bs[128 * 64];
  const int tid = threadIdx.x;
  const int wave = tid >> 6, lane = tid & 63;
  const int quad = lane >> 4, l16 = lane & 15;
  const int lrow = lane >> 3, lch = lane & 7;
  const int scol = (lch ^ lrow) * 8;  // swizzled source col (halfs)
  const int bm = blockIdx.y * 128, bn = blockIdx.x * 128;
  const int wm = (wave >> 1) * 64, wn = (wave & 1) * 64;

  f32x4 acc[4][4] = {};

  for (int k0 = 0; k0 < K; k0 += 64) {
    for (int i = 0; i < 4; ++i) {
      int br = wave * 32 + i * 8;
      gld_lds16(&A[(size_t)(bm + br + lrow) * K + k0 + scol], &As[br * 64]);
      gld_lds16(&Bw[(size_t)(bn + br + lrow) * K + k0 + scol], &Bs[br * 64]);
    }
    __syncthreads();
    for (int ks = 0; ks < 2; ++ks) {
      f16x8 af[4], bf[4];
      for (int mt = 0; mt < 4; ++mt)
        af[mt] = *(const f16x8*)&As[(wm + mt * 16 + l16) * 64 +
                                    (((ks * 4 + quad) ^ (l16 & 7)) * 8)];
      for (int nt = 0; nt < 4; ++nt)
        bf[nt] = *(const f16x8*)&Bs[(wn + nt * 16 + l16) * 64 +
                                    (((ks * 4 + quad) ^ (l16 & 7)) * 8)];
      for (int mt = 0; mt < 4; ++mt)
        for (int nt = 0; nt < 4; ++nt)
          acc[mt][nt] = __builtin_amdgcn_mfma_f32_16x16x32_f16(af[mt], bf[nt], acc[mt][nt], 0, 0, 0);
    }
    __syncthreads();
  }

  for (int mt = 0; mt < 4; ++mt)
    for (int nt = 0; nt < 4; ++nt)
      for (int r = 0; r < 4; ++r) {
        int m = bm + wm + mt * 16 + quad * 4 + r;
        int n = bn + wn + nt * 16 + l16;
        C[(size_t)m * N + n] = (OutT)acc[mt][nt][r];
      }
}

// ---------------------------------------------------------------------------
// Fused split GEMM:  C = Ah@Bh^T + (Ah@Bl^T + Al@Bh^T)/1024
// ---------------------------------------------------------------------------
__global__ __launch_bounds__(256, 2) void gemm_bt_split(
    const _Float16* __restrict__ Ah, const _Float16* __restrict__ Al,
    const _Float16* __restrict__ Bh, const _Float16* __restrict__ Bl,
    float* __restrict__ C, int M, int N, int K) {
  __shared__ _Float16 Ash[128 * 64];
  __shared__ _Float16 Asl[128 * 64];
  __shared__ _Float16 Bsh[128 * 64];
  __shared__ _Float16 Bsl[128 * 64];
  const int tid = threadIdx.x;
  const int wave = tid >> 6, lane = tid & 63;
  const int quad = lane >> 4, l16 = lane & 15;
  const int lrow = lane >> 3, lch = lane & 7;
  const int scol = (lch ^ lrow) * 8;
  const int bm = blockIdx.y * 128, bn = blockIdx.x * 128;
  const int wm = (wave >> 1) * 64, wn = (wave & 1) * 64;

  f32x4 acc_hh[4][4] = {};
  f32x4 acc_cr[4][4] = {};

  for (int k0 = 0; k0 < K; k0 += 64) {
    for (int i = 0; i < 4; ++i) {
      int br = wave * 32 + i * 8;
      size_t ga = (size_t)(bm + br + lrow) * K + k0 + scol;
      size_t gb = (size_t)(bn + br + lrow) * K + k0 + scol;
      gld_lds16(&Ah[ga], &Ash[br * 64]);
      gld_lds16(&Al[ga], &Asl[br * 64]);
      gld_lds16(&Bh[gb], &Bsh[br * 64]);
      gld_lds16(&Bl[gb], &Bsl[br * 64]);
    }
    __syncthreads();
    for (int ks = 0; ks < 2; ++ks) {
      const int sw = ((ks * 4 + quad) ^ (l16 & 7)) * 8;
      f16x8 afh[4], afl[4], bfh[4], bfl[4];
      for (int mt = 0; mt < 4; ++mt) {
        afh[mt] = *(const f16x8*)&Ash[(wm + mt * 16 + l16) * 64 + sw];
        afl[mt] = *(const f16x8*)&Asl[(wm + mt * 16 + l16) * 64 + sw];
      }
      for (int nt = 0; nt < 4; ++nt) {
        bfh[nt] = *(const f16x8*)&Bsh[(wn + nt * 16 + l16) * 64 + sw];
        bfl[nt] = *(const f16x8*)&Bsl[(wn + nt * 16 + l16) * 64 + sw];
      }
      for (int mt = 0; mt < 4; ++mt)
        for (int nt = 0; nt < 4; ++nt) {
          acc_hh[mt][nt] = __builtin_amdgcn_mfma_f32_16x16x32_f16(afh[mt], bfh[nt], acc_hh[mt][nt], 0, 0, 0);
          acc_cr[mt][nt] = __builtin_amdgcn_mfma_f32_16x16x32_f16(afh[mt], bfl[nt], acc_cr[mt][nt], 0, 0, 0);
          acc_cr[mt][nt] = __builtin_amdgcn_mfma_f32_16x16x32_f16(afl[mt], bfh[nt], acc_cr[mt][nt], 0, 0, 0);
        }
    }
    __syncthreads();
  }

  for (int mt = 0; mt < 4; ++mt)
    for (int nt = 0; nt < 4; ++nt)
      for (int r = 0; r < 4; ++r) {
        int m = bm + wm + mt * 16 + quad * 4 + r;
        int n = bn + wn + nt * 16 + l16;
        C[(size_t)m * N + n] = acc_hh[mt][nt][r] + acc_cr[mt][nt][r] * INV_LOSCALE;
      }
}

// ---------------------------------------------------------------------------
// V16 [B,L,H,D] (viewed [BL][E]) -> Vt_g [B][H*D][L]
// ---------------------------------------------------------------------------
__global__ __launch_bounds__(256) void transpose_v(const _Float16* __restrict__ V,
                                                   _Float16* __restrict__ Vt) {
  __shared__ _Float16 T[64][72];
  const int bl0 = blockIdx.x * 64, n0 = blockIdx.y * 64;
  const int tid = threadIdx.x;
  for (int c = 0; c < 2; ++c) {
    int chunk = tid + c * 256;
    int r = chunk >> 3, cc = (chunk & 7) * 8;
    *(uint4*)&T[r][cc] = *(const uint4*)&V[(size_t)(bl0 + r) * Ee + n0 + cc];
  }
  __syncthreads();
  const int b = bl0 >> 11;
  const int k0 = bl0 & (Ll - 1);
  for (int c = 0; c < 2; ++c) {
    int chunk = tid + c * 256;
    int nr = chunk >> 3, kc = (chunk & 7) * 8;
    _Float16 tmp[8];
    for (int j = 0; j < 8; ++j) tmp[j] = T[kc + j][nr];
    *(uint4*)&Vt[((size_t)b * Ee + n0 + nr) * Ll + k0 + kc] = *(uint4*)tmp;
  }
}

// ---------------------------------------------------------------------------
// Fused RMSNorm (fp32) + rotary + outmul -> split fp16 (hi, lo UNSCALED)
// ---------------------------------------------------------------------------
__global__ __launch_bounds__(256) void rmsrope(const float* __restrict__ raw,
                                               const float* __restrict__ scale,
                                               const float* __restrict__ rope,
                                               _Float16* __restrict__ outh,
                                               _Float16* __restrict__ outl, float outmul) {
  int row = blockIdx.x * 4 + (threadIdx.x >> 6);
  int t = threadIdx.x & 63;
  float2 x = *(const float2*)&raw[(size_t)row * Dd + 2 * t];
  float ss = x.x * x.x + x.y * x.y;
  for (int off = 1; off < 64; off <<= 1) ss += __shfl_xor(ss, off);
  float inv = rsqrtf(ss * (1.0f / Dd) + 1e-6f);
  float2 sc = *(const float2*)&scale[2 * t];
  float y0 = x.x * inv * sc.x;
  float y1 = x.y * inv * sc.y;
  int bl = row >> 4;
  float2 cs = *(const float2*)&rope[(size_t)bl * Dd + 2 * t];
  float r0 = (y0 * cs.x - y1 * cs.y) * outmul;
  float r1 = (y1 * cs.x + y0 * cs.y) * outmul;
  _Float16 h[2] = {(_Float16)r0, (_Float16)r1};
  _Float16 l[2] = {(_Float16)(r0 - (float)h[0]), (_Float16)(r1 - (float)h[1])};
  *(uint*)&outh[(size_t)row * Dd + 2 * t] = *(uint*)h;
  *(uint*)&outl[(size_t)row * Dd + 2 * t] = *(uint*)l;
}

// ---------------------------------------------------------------------------
// Flash attention, 512 threads = 8 waves, each wave owns 32 q-rows (2 m-tiles)
// of a 256-row q-tile -> grid = 256 blocks = 1 per CU.
// This round: kt-loop unrolled x2 so `cur` is a compile-time literal (all LDS
// addressing becomes base-reg + immediate); per-lane LDS base pointers hoisted
// (K/V rows, swizzled P store/load); softmax common path has ZERO cross-lane
// ops (lazy max: per-lane compare vs m_r+8, full 16-lane reduce+rescale only
// when __any fires); exp2 via raw v_exp_f32 (domain already log2).
// ---------------------------------------------------------------------------
__global__ __launch_bounds__(512, 2) void attn(const _Float16* __restrict__ Qh_,
                                               const _Float16* __restrict__ Ql_,
                                               const _Float16* __restrict__ Kh_,
                                               const _Float16* __restrict__ Kl_,
                                               const _Float16* __restrict__ Vt_g,
                                               const _Float16* __restrict__ biasp,
                                               _Float16* __restrict__ O) {
  __shared__ _Float16 Ksh[2][64 * 128];   // swizzled, double-buffered (32KB)
  __shared__ _Float16 Ksl[2][64 * 128];   // swizzled, double-buffered (32KB)
  __shared__ _Float16 Vts[2][128 * 64];   // swizzled Vt[d][k], dbuf (32KB)
  __shared__ _Float16 Ps[256 * 64];       // XOR-swizzled P (32KB)

  const int tid = threadIdx.x;
  const int wave = tid >> 6, lane = tid & 63;
  const int quad = lane >> 4, l16 = lane & 15;
  const int lrow8 = lane >> 3, lch8 = lane & 7;
  const int lrow16 = lane >> 4, lch16 = lane & 15;
  const int h = blockIdx.x;
  const int qt = blockIdx.y, q0 = qt * 256;
  const int b = blockIdx.z;

  // Q fragments resident (A-layout)
  f16x8 aqh[2][4], aql[2][4];
  for (int m = 0; m < 2; ++m) {
    size_t qrow = (((size_t)b * Ll + q0 + wave * 32 + m * 16 + l16) * Hh + h) * Dd;
    for (int ks = 0; ks < 4; ++ks) {
      aqh[m][ks] = *(const f16x8*)&Qh_[qrow + ks * 32 + quad * 8];
      aql[m][ks] = *(const f16x8*)&Ql_[qrow + ks * 32 + quad * 8];
    }
  }
  const _Float16* Vbase = Vt_g + ((size_t)b * Ee + h * Dd) * Ll;
  const _Float16* bias_base = biasp + (size_t)(b * 8 + qt) * NT * 16 * 1024 +
                              (size_t)(wave * 2) * 1024 + (size_t)lane * 16;

  // hoisted per-lane LDS bases (all loop indexing becomes immediates)
  const _Float16* kshp = &Ksh[0][l16 * 128];
  const _Float16* kslp = &Ksl[0][l16 * 128];
  const _Float16* vtsp = &Vts[0][l16 * 64];
  int swk[4];
  for (int ks = 0; ks < 4; ++ks) swk[ks] = ((ks * 4 + quad) ^ (l16 & 7)) * 8;
  _Float16* ps_st[4];
  {
    _Float16* base = &Ps[(wave * 32 + quad * 4) * 64 + l16];
    for (int nt = 0; nt < 4; ++nt) ps_st[nt] = base + ((nt ^ quad) << 4);
  }
  const _Float16 *ps_ld0, *ps_ld1;
  {
    const _Float16* base = &Ps[(wave * 32 + l16) * 64];
    int px = ((l16 >> 2) & 3) << 4;
    ps_ld0 = base + ((quad * 8) ^ px);
    ps_ld1 = base + ((32 + quad * 8) ^ px);
  }

  f32x4 o_acc[2][8] = {};
  float m_r[2][4], l_r[2][4];
  for (int m = 0; m < 2; ++m)
    for (int r = 0; r < 4; ++r) { m_r[m][r] = -1e30f; l_r[m][r] = 0.f; }

  auto stage = [&](int nb, int kt) {
    const int k0 = kt * 64;
    for (int i = 0; i < 2; ++i) {
      int br = wave * 8 + i * 4;
      int row = br + lrow16;
      int sc = (lch16 ^ (row & 7)) * 8;
      size_t g = (((size_t)b * Ll + k0 + row) * Hh + h) * Dd + sc;
      gld_lds16(&Kh_[g], &Ksh[nb][br * 128]);
      gld_lds16(&Kl_[g], &Ksl[nb][br * 128]);
    }
    for (int i = 0; i < 2; ++i) {
      int br = wave * 16 + i * 8;
      int row = br + lrow8;
      int sc = (lch8 ^ (row & 7)) * 8;
      gld_lds16(&Vbase[(size_t)row * Ll + k0 + sc], &Vts[nb][br * 64]);
    }
  };

  auto iter = [&](int kt, int cur) {
    // bias fragments FIRST (oldest in vmcnt queue -> waiting on them leaves
    // the staging loads below still outstanding)
    f16x8 bf[2][2];
    {
      const _Float16* bp = bias_base + (size_t)kt * 16384;
      bf[0][0] = *(const f16x8*)&bp[0];
      bf[0][1] = *(const f16x8*)&bp[8];
      bf[1][0] = *(const f16x8*)&bp[1024];
      bf[1][1] = *(const f16x8*)&bp[1032];
    }
    if (kt + 1 < NT) stage(cur ^ 1, kt + 1);

    // S = Q@K^T, hi*hi + both cross terms into one accumulator
    __builtin_amdgcn_s_setprio(1);
    f32x4 s[2][4] = {};
#pragma unroll
    for (int ks = 0; ks < 4; ++ks) {
#pragma unroll
      for (int nt = 0; nt < 4; ++nt) {
        f16x8 bkh = *(const f16x8*)&kshp[cur * 8192 + nt * 2048 + swk[ks]];
        f16x8 bkl = *(const f16x8*)&kslp[cur * 8192 + nt * 2048 + swk[ks]];
#pragma unroll
        for (int m = 0; m < 2; ++m) {
          s[m][nt] = __builtin_amdgcn_mfma_f32_16x16x32_f16(aqh[m][ks], bkh, s[m][nt], 0, 0, 0);
          s[m][nt] = __builtin_amdgcn_mfma_f32_16x16x32_f16(aql[m][ks], bkh, s[m][nt], 0, 0, 0);
          s[m][nt] = __builtin_amdgcn_mfma_f32_16x16x32_f16(aqh[m][ks], bkl, s[m][nt], 0, 0, 0);
        }
      }
    }
    __builtin_amdgcn_s_setprio(0);

    // + bias (already in log2 scale)
#pragma unroll
    for (int m = 0; m < 2; ++m)
#pragma unroll
      for (int nt = 0; nt < 4; ++nt)
#pragma unroll
        for (int r = 0; r < 4; ++r) {
          float bv = (nt < 2) ? (float)bf[m][0][nt * 4 + r] : (float)bf[m][1][nt * 4 + r - 8];
          s[m][nt][r] += bv;
        }

    // lazy online softmax: common path has NO cross-lane ops
    float lmax[2][4];
    bool grow = false;
#pragma unroll
    for (int m = 0; m < 2; ++m)
#pragma unroll
      for (int r = 0; r < 4; ++r) {
        float v = fmaxf(fmaxf(s[m][0][r], s[m][1][r]), fmaxf(s[m][2][r], s[m][3][r]));
        lmax[m][r] = v;
        grow = grow || (v > m_r[m][r] + 8.f);
      }
    if (__any(grow)) {
#pragma unroll
      for (int m = 0; m < 2; ++m)
#pragma unroll
        for (int r = 0; r < 4; ++r) {
          float v = lmax[m][r];
          for (int off = 1; off < 16; off <<= 1) v = fmaxf(v, __shfl_xor(v, off));
          float mn = fmaxf(m_r[m][r], v);
          float alpha = exp2_hw(m_r[m][r] - mn);
          m_r[m][r] = mn;
          l_r[m][r] *= alpha;
          for (int ot = 0; ot < 8; ++ot) o_acc[m][ot][r] *= alpha;
        }
    }
    // P = exp2(s - m) <= 2^8; per-lane partial row sums (reduced once at end)
#pragma unroll
    for (int m = 0; m < 2; ++m)
#pragma unroll
      for (int r = 0; r < 4; ++r) {
        float sum = 0.f;
#pragma unroll
        for (int nt = 0; nt < 4; ++nt) {
          float p = exp2_hw(s[m][nt][r] - m_r[m][r]);
          sum += p;
          ps_st[nt][m * 1024 + r * 64] = (_Float16)p;
        }
        l_r[m][r] += sum;
      }

    // O += P @ V  (P rows are wave-private: no barrier before read)
    __builtin_amdgcn_s_setprio(1);
#pragma unroll
    for (int ks = 0; ks < 2; ++ks) {
      f16x8 ap[2];
      ap[0] = *(const f16x8*)&(ks ? ps_ld1 : ps_ld0)[0];
      ap[1] = *(const f16x8*)&(ks ? ps_ld1 : ps_ld0)[1024];
#pragma unroll
      for (int ot = 0; ot < 8; ++ot) {
        f16x8 bv = *(const f16x8*)&vtsp[cur * 8192 + ot * 1024 + swk[ks]];
        for (int m = 0; m < 2; ++m)
          o_acc[m][ot] = __builtin_amdgcn_mfma_f32_16x16x32_f16(ap[m], bv, o_acc[m][ot], 0, 0, 0);
      }
    }
    __builtin_amdgcn_s_setprio(0);
    // single barrier per iter: protects buf[cur] reads from next iter's stage
    // and (via the compiler's vmcnt drain) publishes buf[cur^1]'s loads.
    __syncthreads();
  };

  stage(0, 0);
  __syncthreads();
  for (int kt = 0; kt < NT; kt += 2) {
    iter(kt, 0);       // cur literal -> all LDS addressing is base+imm
    iter(kt + 1, 1);
  }

  // deferred l reduce across the 16-lane row groups
  for (int m = 0; m < 2; ++m)
    for (int r = 0; r < 4; ++r) {
      float l = l_r[m][r];
      for (int off = 1; off < 16; off <<= 1) l += __shfl_xor(l, off);
      l_r[m][r] = 1.f / l;
    }

  for (int m = 0; m < 2; ++m)
    for (int ot = 0; ot < 8; ++ot)
      for (int r = 0; r < 4; ++r) {
        int mm = q0 + wave * 32 + m * 16 + quad * 4 + r;
        O[(((size_t)b * Ll + mm) * Hh + h) * Dd + ot * 16 + l16] =
            (_Float16)(o_acc[m][ot][r] * l_r[m][r]);
      }
}

// ---------------------------------------------------------------------------
extern "C" void kernel_launch(void* const* d_in, const int* in_sizes, int n_in,
                              void* d_out, int out_size, void* d_ws, size_t ws_size,
                              hipStream_t stream) {
  const float* inputs_q  = (const float*)d_in[0];
  const float* inputs_kv = (const float*)d_in[1];
  const float* bias      = (const float*)d_in[2];
  const float* rope_q    = (const float*)d_in[3];
  const float* rope_k    = (const float*)d_in[4];
  const float* Wq        = (const float*)d_in[5];
  const float* Wk        = (const float*)d_in[6];
  const float* Wv        = (const float*)d_in[7];
  const float* Wo        = (const float*)d_in[8];
  const float* q_scale   = (const float*)d_in[9];
  const float* k_scale   = (const float*)d_in[10];
  float* out = (float*)d_out;

  char* ws = (char*)d_ws;
  size_t o = 0;
  auto alloc = [&](size_t bytes) {
    char* p = ws + o;
    o += (bytes + 255) & ~(size_t)255;
    return p;
  };
  const size_t szX16 = (size_t)BL * Ee * 2;   // 16 MB
  const size_t szW16 = (size_t)Ee * Ee * 2;   // 8 MB
  _Float16* Xq_hi  = (_Float16*)alloc(szX16);
  _Float16* Xq_lo  = (_Float16*)alloc(szX16);
  _Float16* Xkv_hi = (_Float16*)alloc(szX16);
  _Float16* Xkv_lo = (_Float16*)alloc(szX16);
  _Float16* Wq_hi  = (_Float16*)alloc(szW16);
  _Float16* Wq_lo  = (_Float16*)alloc(szW16);
  _Float16* Wk_hi  = (_Float16*)alloc(szW16);
  _Float16* Wk_lo  = (_Float16*)alloc(szW16);
  _Float16* Wv_hi  = (_Float16*)alloc(szW16);
  _Float16* Wo_hi  = (_Float16*)alloc(szW16);
  float* Qraw = (float*)alloc((size_t)BL * Ee * 4);   // 32 MB
  float* Kraw = (float*)alloc((size_t)BL * Ee * 4);   // 32 MB
  _Float16* V16 = (_Float16*)alloc(szX16);
  // aliases (stream-ordered reuse; lifetimes disjoint)
  _Float16* Q16h   = Xq_hi;            // Xq dead after Q projection
  _Float16* Q16l   = Xq_lo;
  _Float16* K16h   = Xkv_hi;           // Xkv dead after K/V projections
  _Float16* K16l   = Xkv_lo;
  _Float16* X16    = (_Float16*)Qraw;  // Qraw dead after rmsrope(Q)
  _Float16* Vt_g   = Wq_hi;            // Wq hi+lo (16MB contig) dead after Q proj
  _Float16* biasp  = (_Float16*)Kraw;  // Kraw dead after rmsrope(K); 16.8MB <= 32MB

  const int nX4 = BL * Ee / 4;
  const int nW4 = Ee * Ee / 4;
  cvt_split<<<nX4 / 256, 256, 0, stream>>>(inputs_q, Xq_hi, Xq_lo, nX4);
  cvt_split<<<nX4 / 256, 256, 0, stream>>>(inputs_kv, Xkv_hi, Xkv_lo, nX4);
  cvt_split<<<nW4 / 256, 256, 0, stream>>>(Wq, Wq_hi, Wq_lo, nW4);
  cvt_split<<<nW4 / 256, 256, 0, stream>>>(Wk, Wk_hi, Wk_lo, nW4);
  cvt_f32_f16<<<nW4 / 256, 256, 0, stream>>>(Wv, Wv_hi, nW4);
  cvt_f32_f16<<<nW4 / 256, 256, 0, stream>>>(Wo, Wo_hi, nW4);

  dim3 gblk(Ee / 128, BL / 128);  // (16, 32)
  gemm_bt_split<<<gblk, 256, 0, stream>>>(Xq_hi, Xq_lo, Wq_hi, Wq_lo, Qraw, BL, Ee, Ee);
  gemm_bt_split<<<gblk, 256, 0, stream>>>(Xkv_hi, Xkv_lo, Wk_hi, Wk_lo, Kraw, BL, Ee, Ee);
  gemm_bt<_Float16><<<gblk, 256, 0, stream>>>(Xkv_hi, Wv_hi, V16, BL, Ee, Ee);

  transpose_v<<<dim3(BL / 64, Ee / 64), 256, 0, stream>>>(V16, Vt_g);

  // Q carries sqrt(D) (faithful div by D^-0.5) AND log2(e) for exp2-domain softmax
  rmsrope<<<BL * Hh / 4, 256, 0, stream>>>(Qraw, q_scale, rope_q, Q16h, Q16l,
                                           sqrtf((float)Dd) * LOG2E);
  rmsrope<<<BL * Hh / 4, 256, 0, stream>>>(Kraw, k_scale, rope_k, K16h, K16l, 1.0f);

  // bias f32 -> fragment-ordered fp16 * LOG2E (into Kraw region, now dead)
  bias_perm<<<dim3(NT, Ll / 128, Bb), 256, 0, stream>>>(bias, biasp);

  attn<<<dim3(Hh, Ll / 256, Bb), 512, 0, stream>>>(Q16h, Q16l, K16h, K16l, Vt_g, biasp, X16);

  gemm_bt<float><<<gblk, 256, 0, stream>>>(X16, Wo_hi, out, BL, Ee, Ee);
}

// Round 4
// 692.076 us; speedup vs baseline: 1.0923x; 1.0923x over previous
//
#include <hip/hip_runtime.h>

// Problem constants
#define Bb 2
#define Ll 2048
#define Ee 2048
#define Hh 16
#define Dd 128
#define BL (Bb * Ll)   // 4096
#define NT (Ll / 64)   // 32 k-tiles in attention
#define LOSCALE 1024.0f
#define INV_LOSCALE (1.0f / 1024.0f)
#define LOG2E 1.442695041f

typedef float f32x4 __attribute__((ext_vector_type(4)));
typedef _Float16 f16x8 __attribute__((ext_vector_type(8)));

// Async global->LDS, 16B per lane. Dest = wave-uniform base + lane*16.
// Source is PER-LANE, so XOR swizzles are applied on the source address.
__device__ __forceinline__ void gld_lds16(const void* g, void* l) {
  __builtin_amdgcn_global_load_lds((const __attribute__((address_space(1))) void*)g,
                                   (__attribute__((address_space(3))) void*)l, 16, 0, 0);
}

// Hardware 2^x (v_exp_f32 semantics ARE exp2). Single transcendental op,
// no libm range-check code. Register-neutral.
__device__ __forceinline__ float exp2_hw(float x) {
  float r;
  asm("v_exp_f32 %0, %1" : "=v"(r) : "v"(x));
  return r;
}

// ---------------------------------------------------------------------------
// f32 -> f16 plain convert (4 elems / thread)
// ---------------------------------------------------------------------------
__global__ __launch_bounds__(256) void cvt_f32_f16(const float* __restrict__ in,
                                                   _Float16* __restrict__ out, int n4) {
  int i = blockIdx.x * 256 + threadIdx.x;
  if (i < n4) {
    float4 f = ((const float4*)in)[i];
    _Float16 o[4] = {(_Float16)f.x, (_Float16)f.y, (_Float16)f.z, (_Float16)f.w};
    ((uint2*)out)[i] = *(uint2*)o;
  }
}

// ---------------------------------------------------------------------------
// f32 -> split fp16: hi = rn(x), lo = rn((x - hi) * 1024)  (eps^2 precision)
// ---------------------------------------------------------------------------
__global__ __launch_bounds__(256) void cvt_split(const float* __restrict__ in,
                                                 _Float16* __restrict__ hi,
                                                 _Float16* __restrict__ lo, int n4) {
  int i = blockIdx.x * 256 + threadIdx.x;
  if (i < n4) {
    float4 f = ((const float4*)in)[i];
    float fa[4] = {f.x, f.y, f.z, f.w};
    _Float16 h[4], l[4];
    for (int j = 0; j < 4; ++j) {
      h[j] = (_Float16)fa[j];
      l[j] = (_Float16)((fa[j] - (float)h[j]) * LOSCALE);
    }
    ((uint2*)hi)[i] = *(uint2*)h;
    ((uint2*)lo)[i] = *(uint2*)l;
  }
}

// ---------------------------------------------------------------------------
// bias f32 [b][q][k] -> fp16*LOG2E in MFMA-fragment order:
//   [b][qt256][kt][idx16][lane][16], idx16 = wave*2 + m  (wave owns 32 q-rows)
// ---------------------------------------------------------------------------
__global__ __launch_bounds__(256) void bias_perm(const float* __restrict__ bias,
                                                 _Float16* __restrict__ out) {
  __shared__ float T[128][68];
  const int kt = blockIdx.x, qt = blockIdx.y, b = blockIdx.z;  // qt: 128-row units
  const float* src = bias + ((size_t)b * Ll + qt * 128) * Ll + kt * 64;
  const int t = threadIdx.x;
  for (int c = 0; c < 8; ++c) {
    int idx = c * 256 + t;              // 0..2047 float4 chunks
    int r = idx >> 4, col4 = (idx & 15) * 4;
    float4 v = *(const float4*)&src[(size_t)r * Ll + col4];
    T[r][col4 + 0] = v.x; T[r][col4 + 1] = v.y;
    T[r][col4 + 2] = v.z; T[r][col4 + 3] = v.w;
  }
  __syncthreads();
  _Float16* dst = out + ((((size_t)(b * 8 + (qt >> 1)) * NT + kt) * 16 + (qt & 1) * 8) * 64) * 16;
  for (int s = 0; s < 2; ++s) {
    int slot = t + s * 256;             // 0..511 = w16*64 + lane
    int w = slot >> 6, lane = slot & 63;
    int quad = lane >> 4, l16 = lane & 15;
    _Float16 vals[16];
    for (int nt = 0; nt < 4; ++nt)
      for (int r = 0; r < 4; ++r)
        vals[nt * 4 + r] = (_Float16)(T[w * 16 + quad * 4 + r][nt * 16 + l16] * LOG2E);
    *(uint4*)&dst[((size_t)w * 64 + lane) * 16] = *(uint4*)&vals[0];
    *(uint4*)&dst[((size_t)w * 64 + lane) * 16 + 8] = *(uint4*)&vals[8];
  }
}

// ---------------------------------------------------------------------------
// Plain GEMM:  C[M,N] = A[M,K] @ Bw[N,K]^T.
// ---------------------------------------------------------------------------
template <typename OutT>
__global__ __launch_bounds__(256, 2) void gemm_bt(const _Float16* __restrict__ A,
                                                  const _Float16* __restrict__ Bw,
                                                  OutT* __restrict__ C, int M, int N, int K) {
  __shared__ _Float16 As[128 * 64];
  __shared__ _Float16 Bs[128 * 64];
  const int tid = threadIdx.x;
  const int wave = tid >> 6, lane = tid & 63;
  const int quad = lane >> 4, l16 = lane & 15;
  const int lrow = lane >> 3, lch = lane & 7;
  const int scol = (lch ^ lrow) * 8;  // swizzled source col (halfs)
  const int bm = blockIdx.y * 128, bn = blockIdx.x * 128;
  const int wm = (wave >> 1) * 64, wn = (wave & 1) * 64;

  f32x4 acc[4][4] = {};

  for (int k0 = 0; k0 < K; k0 += 64) {
    for (int i = 0; i < 4; ++i) {
      int br = wave * 32 + i * 8;
      gld_lds16(&A[(size_t)(bm + br + lrow) * K + k0 + scol], &As[br * 64]);
      gld_lds16(&Bw[(size_t)(bn + br + lrow) * K + k0 + scol], &Bs[br * 64]);
    }
    __syncthreads();
    for (int ks = 0; ks < 2; ++ks) {
      f16x8 af[4], bf[4];
      for (int mt = 0; mt < 4; ++mt)
        af[mt] = *(const f16x8*)&As[(wm + mt * 16 + l16) * 64 +
                                    (((ks * 4 + quad) ^ (l16 & 7)) * 8)];
      for (int nt = 0; nt < 4; ++nt)
        bf[nt] = *(const f16x8*)&Bs[(wn + nt * 16 + l16) * 64 +
                                    (((ks * 4 + quad) ^ (l16 & 7)) * 8)];
      for (int mt = 0; mt < 4; ++mt)
        for (int nt = 0; nt < 4; ++nt)
          acc[mt][nt] = __builtin_amdgcn_mfma_f32_16x16x32_f16(af[mt], bf[nt], acc[mt][nt], 0, 0, 0);
    }
    __syncthreads();
  }

  for (int mt = 0; mt < 4; ++mt)
    for (int nt = 0; nt < 4; ++nt)
      for (int r = 0; r < 4; ++r) {
        int m = bm + wm + mt * 16 + quad * 4 + r;
        int n = bn + wn + nt * 16 + l16;
        C[(size_t)m * N + n] = (OutT)acc[mt][nt][r];
      }
}

// ---------------------------------------------------------------------------
// Fused split GEMM:  C = Ah@Bh^T + (Ah@Bl^T + Al@Bh^T)/1024
// ---------------------------------------------------------------------------
__global__ __launch_bounds__(256, 2) void gemm_bt_split(
    const _Float16* __restrict__ Ah, const _Float16* __restrict__ Al,
    const _Float16* __restrict__ Bh, const _Float16* __restrict__ Bl,
    float* __restrict__ C, int M, int N, int K) {
  __shared__ _Float16 Ash[128 * 64];
  __shared__ _Float16 Asl[128 * 64];
  __shared__ _Float16 Bsh[128 * 64];
  __shared__ _Float16 Bsl[128 * 64];
  const int tid = threadIdx.x;
  const int wave = tid >> 6, lane = tid & 63;
  const int quad = lane >> 4, l16 = lane & 15;
  const int lrow = lane >> 3, lch = lane & 7;
  const int scol = (lch ^ lrow) * 8;
  const int bm = blockIdx.y * 128, bn = blockIdx.x * 128;
  const int wm = (wave >> 1) * 64, wn = (wave & 1) * 64;

  f32x4 acc_hh[4][4] = {};
  f32x4 acc_cr[4][4] = {};

  for (int k0 = 0; k0 < K; k0 += 64) {
    for (int i = 0; i < 4; ++i) {
      int br = wave * 32 + i * 8;
      size_t ga = (size_t)(bm + br + lrow) * K + k0 + scol;
      size_t gb = (size_t)(bn + br + lrow) * K + k0 + scol;
      gld_lds16(&Ah[ga], &Ash[br * 64]);
      gld_lds16(&Al[ga], &Asl[br * 64]);
      gld_lds16(&Bh[gb], &Bsh[br * 64]);
      gld_lds16(&Bl[gb], &Bsl[br * 64]);
    }
    __syncthreads();
    for (int ks = 0; ks < 2; ++ks) {
      const int sw = ((ks * 4 + quad) ^ (l16 & 7)) * 8;
      f16x8 afh[4], afl[4], bfh[4], bfl[4];
      for (int mt = 0; mt < 4; ++mt) {
        afh[mt] = *(const f16x8*)&Ash[(wm + mt * 16 + l16) * 64 + sw];
        afl[mt] = *(const f16x8*)&Asl[(wm + mt * 16 + l16) * 64 + sw];
      }
      for (int nt = 0; nt < 4; ++nt) {
        bfh[nt] = *(const f16x8*)&Bsh[(wn + nt * 16 + l16) * 64 + sw];
        bfl[nt] = *(const f16x8*)&Bsl[(wn + nt * 16 + l16) * 64 + sw];
      }
      for (int mt = 0; mt < 4; ++mt)
        for (int nt = 0; nt < 4; ++nt) {
          acc_hh[mt][nt] = __builtin_amdgcn_mfma_f32_16x16x32_f16(afh[mt], bfh[nt], acc_hh[mt][nt], 0, 0, 0);
          acc_cr[mt][nt] = __builtin_amdgcn_mfma_f32_16x16x32_f16(afh[mt], bfl[nt], acc_cr[mt][nt], 0, 0, 0);
          acc_cr[mt][nt] = __builtin_amdgcn_mfma_f32_16x16x32_f16(afl[mt], bfh[nt], acc_cr[mt][nt], 0, 0, 0);
        }
    }
    __syncthreads();
  }

  for (int mt = 0; mt < 4; ++mt)
    for (int nt = 0; nt < 4; ++nt)
      for (int r = 0; r < 4; ++r) {
        int m = bm + wm + mt * 16 + quad * 4 + r;
        int n = bn + wn + nt * 16 + l16;
        C[(size_t)m * N + n] = acc_hh[mt][nt][r] + acc_cr[mt][nt][r] * INV_LOSCALE;
      }
}

// ---------------------------------------------------------------------------
// V16 [B,L,H,D] (viewed [BL][E]) -> Vt_g [B][H*D][L]
// ---------------------------------------------------------------------------
__global__ __launch_bounds__(256) void transpose_v(const _Float16* __restrict__ V,
                                                   _Float16* __restrict__ Vt) {
  __shared__ _Float16 T[64][72];
  const int bl0 = blockIdx.x * 64, n0 = blockIdx.y * 64;
  const int tid = threadIdx.x;
  for (int c = 0; c < 2; ++c) {
    int chunk = tid + c * 256;
    int r = chunk >> 3, cc = (chunk & 7) * 8;
    *(uint4*)&T[r][cc] = *(const uint4*)&V[(size_t)(bl0 + r) * Ee + n0 + cc];
  }
  __syncthreads();
  const int b = bl0 >> 11;
  const int k0 = bl0 & (Ll - 1);
  for (int c = 0; c < 2; ++c) {
    int chunk = tid + c * 256;
    int nr = chunk >> 3, kc = (chunk & 7) * 8;
    _Float16 tmp[8];
    for (int j = 0; j < 8; ++j) tmp[j] = T[kc + j][nr];
    *(uint4*)&Vt[((size_t)b * Ee + n0 + nr) * Ll + k0 + kc] = *(uint4*)tmp;
  }
}

// ---------------------------------------------------------------------------
// Fused RMSNorm (fp32) + rotary + outmul -> split fp16 (hi, lo UNSCALED)
// ---------------------------------------------------------------------------
__global__ __launch_bounds__(256) void rmsrope(const float* __restrict__ raw,
                                               const float* __restrict__ scale,
                                               const float* __restrict__ rope,
                                               _Float16* __restrict__ outh,
                                               _Float16* __restrict__ outl, float outmul) {
  int row = blockIdx.x * 4 + (threadIdx.x >> 6);
  int t = threadIdx.x & 63;
  float2 x = *(const float2*)&raw[(size_t)row * Dd + 2 * t];
  float ss = x.x * x.x + x.y * x.y;
  for (int off = 1; off < 64; off <<= 1) ss += __shfl_xor(ss, off);
  float inv = rsqrtf(ss * (1.0f / Dd) + 1e-6f);
  float2 sc = *(const float2*)&scale[2 * t];
  float y0 = x.x * inv * sc.x;
  float y1 = x.y * inv * sc.y;
  int bl = row >> 4;
  float2 cs = *(const float2*)&rope[(size_t)bl * Dd + 2 * t];
  float r0 = (y0 * cs.x - y1 * cs.y) * outmul;
  float r1 = (y1 * cs.x + y0 * cs.y) * outmul;
  _Float16 h[2] = {(_Float16)r0, (_Float16)r1};
  _Float16 l[2] = {(_Float16)(r0 - (float)h[0]), (_Float16)(r1 - (float)h[1])};
  *(uint*)&outh[(size_t)row * Dd + 2 * t] = *(uint*)h;
  *(uint*)&outl[(size_t)row * Dd + 2 * t] = *(uint*)l;
}

// ---------------------------------------------------------------------------
// Flash attention, 512 threads = 8 waves, each wave owns 32 q-rows (2 m-tiles)
// of a 256-row q-tile -> grid = 256 blocks = 1 per CU.
// Structure = R2 (runtime cur, inline LDS addressing — proven spill-free).
// VALU cuts vs R2 (both register-neutral):
//  - exp2 via raw v_exp_f32 (domain already log2; libm exp2f was ~10 instrs)
//  - lazy max: common path is per-lane 3-fmax + compare; the 32-shfl reduce
//    + rescale runs only when __any(per-lane max > m_r+8) fires (the lane
//    holding the row max always triggers it -> conservative & exact).
// ---------------------------------------------------------------------------
__global__ __launch_bounds__(512, 2) void attn(const _Float16* __restrict__ Qh_,
                                               const _Float16* __restrict__ Ql_,
                                               const _Float16* __restrict__ Kh_,
                                               const _Float16* __restrict__ Kl_,
                                               const _Float16* __restrict__ Vt_g,
                                               const _Float16* __restrict__ biasp,
                                               _Float16* __restrict__ O) {
  __shared__ _Float16 Ksh[2][64 * 128];   // swizzled, double-buffered
  __shared__ _Float16 Ksl[2][64 * 128];   // swizzled, double-buffered
  __shared__ _Float16 Vts[2][128 * 64];   // swizzled Vt[d][k], double-buffered
  __shared__ _Float16 Ps[256 * 64];       // XOR-swizzled P

  const int tid = threadIdx.x;
  const int wave = tid >> 6, lane = tid & 63;
  const int quad = lane >> 4, l16 = lane & 15;
  const int lrow8 = lane >> 3, lch8 = lane & 7;
  const int lrow16 = lane >> 4, lch16 = lane & 15;
  const int h = blockIdx.x;
  const int qt = blockIdx.y, q0 = qt * 256;
  const int b = blockIdx.z;

  // Q fragments resident (A-layout): wave's rows q0 + wave*32 + m*16 + l16
  f16x8 aqh[2][4], aql[2][4];
  for (int m = 0; m < 2; ++m) {
    size_t qrow = (((size_t)b * Ll + q0 + wave * 32 + m * 16 + l16) * Hh + h) * Dd;
    for (int ks = 0; ks < 4; ++ks) {
      aqh[m][ks] = *(const f16x8*)&Qh_[qrow + ks * 32 + quad * 8];
      aql[m][ks] = *(const f16x8*)&Ql_[qrow + ks * 32 + quad * 8];
    }
  }
  const _Float16* Vbase = Vt_g + ((size_t)b * Ee + h * Dd) * Ll;
  // bias: [b][qt][kt][wave*2+m][lane][16]; per-iter stride 16*1024 halfs
  const _Float16* bias_base = biasp + (size_t)(b * 8 + qt) * NT * 16 * 1024 +
                              (size_t)(wave * 2) * 1024 + (size_t)lane * 16;

  f32x4 o_acc[2][8] = {};
  float m_r[2][4], l_r[2][4];
  for (int m = 0; m < 2; ++m)
    for (int r = 0; r < 4; ++r) { m_r[m][r] = -1e30f; l_r[m][r] = 0.f; }

  auto stage = [&](int nb, int kt) {
    const int k0 = kt * 64;
    // K hi/lo: 64 rows x 256B; each wave stages 8 rows (2 calls x 4 rows)
    for (int i = 0; i < 2; ++i) {
      int br = wave * 8 + i * 4;
      int row = br + lrow16;
      int sc = (lch16 ^ (row & 7)) * 8;
      size_t g = (((size_t)b * Ll + k0 + row) * Hh + h) * Dd + sc;
      gld_lds16(&Kh_[g], &Ksh[nb][br * 128]);
      gld_lds16(&Kl_[g], &Ksl[nb][br * 128]);
    }
    // V^T: 128 rows x 128B; each wave stages 16 rows (2 calls x 8 rows)
    for (int i = 0; i < 2; ++i) {
      int br = wave * 16 + i * 8;
      int row = br + lrow8;
      int sc = (lch8 ^ (row & 7)) * 8;
      gld_lds16(&Vbase[(size_t)row * Ll + k0 + sc], &Vts[nb][br * 64]);
    }
  };

  stage(0, 0);
  __syncthreads();

  for (int kt = 0; kt < NT; ++kt) {
    const int cur = kt & 1;

    // bias fragments FIRST (oldest in vmcnt queue -> their wait leaves the
    // staging loads below outstanding)
    f16x8 bf[2][2];
    for (int m = 0; m < 2; ++m) {
      const _Float16* bp = bias_base + ((size_t)kt * 16 + m) * 1024;
      bf[m][0] = *(const f16x8*)&bp[0];
      bf[m][1] = *(const f16x8*)&bp[8];
    }
    // issue NEXT tile's staging: latency overlaps this tile's compute
    if (kt + 1 < NT) stage(cur ^ 1, kt + 1);

    // S = Q@K^T, hi*hi + cross terms into one accumulator (lo unscaled)
    __builtin_amdgcn_s_setprio(1);
    f32x4 s[2][4] = {};
    for (int ks = 0; ks < 4; ++ks) {
      const int sw = ((ks * 4 + quad) ^ (l16 & 7)) * 8;
      for (int nt = 0; nt < 4; ++nt) {
        f16x8 bkh = *(const f16x8*)&Ksh[cur][(nt * 16 + l16) * 128 + sw];
        f16x8 bkl = *(const f16x8*)&Ksl[cur][(nt * 16 + l16) * 128 + sw];
        for (int m = 0; m < 2; ++m) {
          s[m][nt] = __builtin_amdgcn_mfma_f32_16x16x32_f16(aqh[m][ks], bkh, s[m][nt], 0, 0, 0);
          s[m][nt] = __builtin_amdgcn_mfma_f32_16x16x32_f16(aql[m][ks], bkh, s[m][nt], 0, 0, 0);
          s[m][nt] = __builtin_amdgcn_mfma_f32_16x16x32_f16(aqh[m][ks], bkl, s[m][nt], 0, 0, 0);
        }
      }
    }
    __builtin_amdgcn_s_setprio(0);

    // + bias (already in log2 scale)
#pragma unroll
    for (int m = 0; m < 2; ++m)
#pragma unroll
      for (int nt = 0; nt < 4; ++nt)
#pragma unroll
        for (int r = 0; r < 4; ++r) {
          float bv = (nt < 2) ? (float)bf[m][0][nt * 4 + r] : (float)bf[m][1][nt * 4 + r - 8];
          s[m][nt][r] += bv;
        }

    // lazy online softmax (log2 domain): no cross-lane ops on the common path
    bool grow = false;
#pragma unroll
    for (int m = 0; m < 2; ++m)
#pragma unroll
      for (int r = 0; r < 4; ++r) {
        float v = fmaxf(fmaxf(s[m][0][r], s[m][1][r]), fmaxf(s[m][2][r], s[m][3][r]));
        grow = grow || (v > m_r[m][r] + 8.f);
      }
    if (__any(grow)) {
#pragma unroll
      for (int m = 0; m < 2; ++m)
#pragma unroll
        for (int r = 0; r < 4; ++r) {
          float v = fmaxf(fmaxf(s[m][0][r], s[m][1][r]), fmaxf(s[m][2][r], s[m][3][r]));
          for (int off = 1; off < 16; off <<= 1) v = fmaxf(v, __shfl_xor(v, off));
          float mn = fmaxf(m_r[m][r], v);
          float alpha = exp2_hw(m_r[m][r] - mn);
          m_r[m][r] = mn;
          l_r[m][r] *= alpha;
          for (int ot = 0; ot < 8; ++ot) o_acc[m][ot][r] *= alpha;
        }
    }
    // P = exp2(s - m) <= 2^8; per-lane partial row sums (reduced once at end)
#pragma unroll
    for (int m = 0; m < 2; ++m)
#pragma unroll
      for (int r = 0; r < 4; ++r) {
        int row = wave * 32 + m * 16 + quad * 4 + r;
        float sum = 0.f;
#pragma unroll
        for (int nt = 0; nt < 4; ++nt) {
          float p = exp2_hw(s[m][nt][r] - m_r[m][r]);
          sum += p;
          int col = nt * 16 + l16;
          Ps[row * 64 + (col ^ (((row >> 2) & 3) << 4))] = (_Float16)p;
        }
        l_r[m][r] += sum;
      }

    // O += P @ V  (P rows are wave-private: no barrier needed before read)
    __builtin_amdgcn_s_setprio(1);
    for (int ks = 0; ks < 2; ++ks) {
      const int sw = ((ks * 4 + quad) ^ (l16 & 7)) * 8;
      f16x8 ap[2];
      for (int m = 0; m < 2; ++m) {
        int prow = wave * 32 + m * 16 + l16;
        ap[m] = *(const f16x8*)&Ps[prow * 64 +
                                   ((ks * 32 + quad * 8) ^ (((l16 >> 2) & 3) << 4))];
      }
      for (int ot = 0; ot < 8; ++ot) {
        f16x8 bv = *(const f16x8*)&Vts[cur][(ot * 16 + l16) * 64 + sw];
        for (int m = 0; m < 2; ++m)
          o_acc[m][ot] = __builtin_amdgcn_mfma_f32_16x16x32_f16(ap[m], bv, o_acc[m][ot], 0, 0, 0);
      }
    }
    __builtin_amdgcn_s_setprio(0);
    // single barrier per iter: protects buf[cur] reads from next iter's stage
    // and (via the compiler's vmcnt drain) publishes buf[cur^1]'s loads.
    __syncthreads();
  }

  // deferred l reduce across the 16-lane row groups
  for (int m = 0; m < 2; ++m)
    for (int r = 0; r < 4; ++r) {
      float l = l_r[m][r];
      for (int off = 1; off < 16; off <<= 1) l += __shfl_xor(l, off);
      l_r[m][r] = 1.f / l;
    }

  for (int m = 0; m < 2; ++m)
    for (int ot = 0; ot < 8; ++ot)
      for (int r = 0; r < 4; ++r) {
        int mm = q0 + wave * 32 + m * 16 + quad * 4 + r;
        O[(((size_t)b * Ll + mm) * Hh + h) * Dd + ot * 16 + l16] =
            (_Float16)(o_acc[m][ot][r] * l_r[m][r]);
      }
}

// ---------------------------------------------------------------------------
extern "C" void kernel_launch(void* const* d_in, const int* in_sizes, int n_in,
                              void* d_out, int out_size, void* d_ws, size_t ws_size,
                              hipStream_t stream) {
  const float* inputs_q  = (const float*)d_in[0];
  const float* inputs_kv = (const float*)d_in[1];
  const float* bias      = (const float*)d_in[2];
  const float* rope_q    = (const float*)d_in[3];
  const float* rope_k    = (const float*)d_in[4];
  const float* Wq        = (const float*)d_in[5];
  const float* Wk        = (const float*)d_in[6];
  const float* Wv        = (const float*)d_in[7];
  const float* Wo        = (const float*)d_in[8];
  const float* q_scale   = (const float*)d_in[9];
  const float* k_scale   = (const float*)d_in[10];
  float* out = (float*)d_out;

  char* ws = (char*)d_ws;
  size_t o = 0;
  auto alloc = [&](size_t bytes) {
    char* p = ws + o;
    o += (bytes + 255) & ~(size_t)255;
    return p;
  };
  const size_t szX16 = (size_t)BL * Ee * 2;   // 16 MB
  const size_t szW16 = (size_t)Ee * Ee * 2;   // 8 MB
  _Float16* Xq_hi  = (_Float16*)alloc(szX16);
  _Float16* Xq_lo  = (_Float16*)alloc(szX16);
  _Float16* Xkv_hi = (_Float16*)alloc(szX16);
  _Float16* Xkv_lo = (_Float16*)alloc(szX16);
  _Float16* Wq_hi  = (_Float16*)alloc(szW16);
  _Float16* Wq_lo  = (_Float16*)alloc(szW16);
  _Float16* Wk_hi  = (_Float16*)alloc(szW16);
  _Float16* Wk_lo  = (_Float16*)alloc(szW16);
  _Float16* Wv_hi  = (_Float16*)alloc(szW16);
  _Float16* Wo_hi  = (_Float16*)alloc(szW16);
  float* Qraw = (float*)alloc((size_t)BL * Ee * 4);   // 32 MB
  float* Kraw = (float*)alloc((size_t)BL * Ee * 4);   // 32 MB
  _Float16* V16 = (_Float16*)alloc(szX16);
  // aliases (stream-ordered reuse; lifetimes disjoint)
  _Float16* Q16h   = Xq_hi;            // Xq dead after Q projection
  _Float16* Q16l   = Xq_lo;
  _Float16* K16h   = Xkv_hi;           // Xkv dead after K/V projections
  _Float16* K16l   = Xkv_lo;
  _Float16* X16    = (_Float16*)Qraw;  // Qraw dead after rmsrope(Q)
  _Float16* Vt_g   = Wq_hi;            // Wq hi+lo (16MB contig) dead after Q proj
  _Float16* biasp  = (_Float16*)Kraw;  // Kraw dead after rmsrope(K); 16.8MB <= 32MB

  const int nX4 = BL * Ee / 4;
  const int nW4 = Ee * Ee / 4;
  cvt_split<<<nX4 / 256, 256, 0, stream>>>(inputs_q, Xq_hi, Xq_lo, nX4);
  cvt_split<<<nX4 / 256, 256, 0, stream>>>(inputs_kv, Xkv_hi, Xkv_lo, nX4);
  cvt_split<<<nW4 / 256, 256, 0, stream>>>(Wq, Wq_hi, Wq_lo, nW4);
  cvt_split<<<nW4 / 256, 256, 0, stream>>>(Wk, Wk_hi, Wk_lo, nW4);
  cvt_f32_f16<<<nW4 / 256, 256, 0, stream>>>(Wv, Wv_hi, nW4);
  cvt_f32_f16<<<nW4 / 256, 256, 0, stream>>>(Wo, Wo_hi, nW4);

  dim3 gblk(Ee / 128, BL / 128);  // (16, 32)
  gemm_bt_split<<<gblk, 256, 0, stream>>>(Xq_hi, Xq_lo, Wq_hi, Wq_lo, Qraw, BL, Ee, Ee);
  gemm_bt_split<<<gblk, 256, 0, stream>>>(Xkv_hi, Xkv_lo, Wk_hi, Wk_lo, Kraw, BL, Ee, Ee);
  gemm_bt<_Float16><<<gblk, 256, 0, stream>>>(Xkv_hi, Wv_hi, V16, BL, Ee, Ee);

  transpose_v<<<dim3(BL / 64, Ee / 64), 256, 0, stream>>>(V16, Vt_g);

  // Q carries sqrt(D) (faithful div by D^-0.5) AND log2(e) for exp2-domain softmax
  rmsrope<<<BL * Hh / 4, 256, 0, stream>>>(Qraw, q_scale, rope_q, Q16h, Q16l,
                                           sqrtf((float)Dd) * LOG2E);
  rmsrope<<<BL * Hh / 4, 256, 0, stream>>>(Kraw, k_scale, rope_k, K16h, K16l, 1.0f);

  // bias f32 -> fragment-ordered fp16 * LOG2E (into Kraw region, now dead)
  bias_perm<<<dim3(NT, Ll / 128, Bb), 256, 0, stream>>>(bias, biasp);

  attn<<<dim3(Hh, Ll / 256, Bb), 512, 0, stream>>>(Q16h, Q16l, K16h, K16l, Vt_g, biasp, X16);

  gemm_bt<float><<<gblk, 256, 0, stream>>>(X16, Wo_hi, out, BL, Ee, Ee);
}